// Round 1
// baseline (52.487 us; speedup 1.0000x reference)
//
#include <hip/hip_runtime.h>
#include <hip/hip_bf16.h>

// out[i,j] = max_{x,y} ( -sqrt((x-i)^2 + (y-j)^2) - f[x,y] )
//          = - min_{x,y} ( sqrt((x-i)^2 + (y-j)^2) + f[x,y] )
// H = W = 96, HW = 9216. One wave (64 lanes) per output pixel.
// Candidate set is scanned as 48 row-pairs; each row-pair = 192 candidates
// = exactly 3 full 64-lane passes (lcm structure), so every lane is active
// in every pass. Per-lane dy^2 for the 3-pass cycle is loop-invariant.

#define H 96
#define W 96
#define HW (H * W)

__global__ __launch_bounds__(64) void mindist_kernel(
    const float* __restrict__ f, float* __restrict__ out) {
    const int pix   = blockIdx.x;        // global pixel over all B*C planes
    const int plane = pix / HW;          // wave-uniform
    const int p     = pix - plane * HW;  // pixel within plane
    const int i     = p / W;             // output row  (x)
    const int j     = p - i * W;         // output col  (y)
    const int lane  = threadIdx.x;       // 0..63

    const float* fp = f + plane * HW;

    // 3-pass cycle per row-pair (rows 2r, 2r+1), flat index k = r*192 + pass*64 + lane:
    //   pass0: row 2r,   y = lane
    //   pass1: lane<32: row 2r, y = 64+lane ; lane>=32: row 2r+1, y = lane-32
    //   pass2: row 2r+1, y = 32+lane
    const float dy0 = (float)(lane - j);
    const int   y1i = (lane < 32) ? (64 + lane) : (lane - 32);
    const float dy1 = (float)(y1i - j);
    const float dy2 = (float)(32 + lane - j);
    const float c0 = dy0 * dy0;
    const float c1 = dy1 * dy1;
    const float c2 = dy2 * dy2;
    const float b1 = (float)(lane >> 5);   // row offset for pass1: 0 or 1

    float m = 1e30f;
    #pragma unroll 4
    for (int r = 0; r < H / 2; ++r) {
        const float u  = (float)(2 * r - i);   // dx for row 2r (wave-uniform)
        const float u1 = u + b1;               // dx for pass1 (per-lane)
        const float u2 = u + 1.0f;             // dx for row 2r+1
        const float dx2_0 = u  * u;
        const float dx2_1 = u1 * u1;
        const float dx2_2 = u2 * u2;

        const int base = r * 192;
        const float f0 = fp[base +       lane];
        const float f1 = fp[base +  64 + lane];
        const float f2 = fp[base + 128 + lane];

        const float t0 = sqrtf(dx2_0 + c0) + f0;
        const float t1 = sqrtf(dx2_1 + c1) + f1;
        const float t2 = sqrtf(dx2_2 + c2) + f2;

        m = fminf(m, fminf(t0, fminf(t1, t2)));
    }

    // wave64 min-reduce
    #pragma unroll
    for (int off = 32; off >= 1; off >>= 1)
        m = fminf(m, __shfl_xor(m, off));

    if (lane == 0) out[pix] = -m;
}

extern "C" void kernel_launch(void* const* d_in, const int* in_sizes, int n_in,
                              void* d_out, int out_size, void* d_ws, size_t ws_size,
                              hipStream_t stream) {
    const float* f = (const float*)d_in[0];
    float* out = (float*)d_out;
    const int n_pix = out_size;          // B*C*H*W, one wave per pixel
    mindist_kernel<<<dim3(n_pix), dim3(64), 0, stream>>>(f, out);
}

// Round 2
// 20.306 us; speedup vs baseline: 2.5848x; 2.5848x over previous
//
#include <hip/hip_runtime.h>
#include <hip/hip_bf16.h>

// out[i,j] = -min_{x,y}( sqrt((x-i)^2+(y-j)^2) + f[x,y] ),  H=W=96.
// Pruning: candidate value >= |x-i| + row_min[x], and >= |x-i| + glob_min.
// Scan rows outward from i; skip rows whose bound >= current wave-best; break
// when |dx| + glob_min >= wave-best (all further rows pruned).

#define H 96
#define W 96
#define HW (H * W)

__device__ __forceinline__ float wave_min(float m) {
#pragma unroll
    for (int off = 32; off >= 1; off >>= 1)
        m = fminf(m, __shfl_xor(m, off));
    return m;
}

// Kernel A: per-plane row minima (H floats) + global min -> ws[plane*(H+1)+...]
__global__ __launch_bounds__(128) void rowmin_kernel(
    const float* __restrict__ f, float* __restrict__ ws) {
    const int plane = blockIdx.x;
    const float* fp = f + plane * HW;
    float* wp = ws + plane * (H + 1);
    __shared__ float s[H];
    const int t = threadIdx.x;
    if (t < H) {
        const float* row = fp + t * W;
        float m = row[0];
#pragma unroll 8
        for (int c = 1; c < W; ++c) m = fminf(m, row[c]);
        s[t] = m;
        wp[t] = m;
    }
    __syncthreads();
    if (t < 64) {
        float m = fminf(s[t], s[64 + (t & 31)]);  // 64..95 covered (dups ok)
        m = wave_min(m);
        if (t == 0) wp[H] = m;
    }
}

// Kernel B: one wave per output pixel; 4 waves (4 pixels) per 256-thread block.
__global__ __launch_bounds__(256) void mindist_kernel(
    const float* __restrict__ f, const float* __restrict__ ws,
    float* __restrict__ out, int n_pix) {
    const int wid  = threadIdx.x >> 6;
    const int lane = threadIdx.x & 63;
    const int pix  = blockIdx.x * 4 + wid;
    if (pix >= n_pix) return;
    const int plane = pix / HW;
    const int p     = pix - plane * HW;
    const int i     = p / W;
    const int j     = p - i * W;

    const float* fp   = f + plane * HW;
    const float* rmin = ws + plane * (H + 1);
    const float  glob = rmin[H];

    // column coverage per row: pass1 = lane (0..63), pass2 = 64+(lane&31)
    // (cols 64..95 evaluated twice by the two half-waves — harmless for min)
    const int   l2  = 64 + (lane & 31);
    const float dy1 = (float)(lane - j);
    const float dy2 = (float)(l2 - j);
    const float c1  = dy1 * dy1;
    const float c2  = dy2 * dy2;

    // level 0: row i (dx = 0)
    float m;
    {
        const float* row = fp + i * W;
        const float t1 = __builtin_amdgcn_sqrtf(c1) + row[lane];
        const float t2 = __builtin_amdgcn_sqrtf(c2) + row[l2];
        m = fminf(t1, t2);
    }
    float mr = wave_min(m);

    for (int d = 1; d < H; ++d) {
        const float dxf = (float)d;
        if (dxf + glob >= mr) break;          // all remaining rows pruned
        const float dx2 = dxf * dxf;
        const int xu = i - d, xd = i + d;
        if (xu >= 0 && dxf + rmin[xu] < mr) { // uniform branch
            const float* row = fp + xu * W;
            const float t1 = __builtin_amdgcn_sqrtf(dx2 + c1) + row[lane];
            const float t2 = __builtin_amdgcn_sqrtf(dx2 + c2) + row[l2];
            m = fminf(m, fminf(t1, t2));
        }
        if (xd < H && dxf + rmin[xd] < mr) {  // uniform branch
            const float* row = fp + xd * W;
            const float t1 = __builtin_amdgcn_sqrtf(dx2 + c1) + row[lane];
            const float t2 = __builtin_amdgcn_sqrtf(dx2 + c2) + row[l2];
            m = fminf(m, fminf(t1, t2));
        }
        mr = wave_min(m);
    }

    if (lane == 0) out[pix] = -mr;
}

extern "C" void kernel_launch(void* const* d_in, const int* in_sizes, int n_in,
                              void* d_out, int out_size, void* d_ws, size_t ws_size,
                              hipStream_t stream) {
    const float* f = (const float*)d_in[0];
    float* out = (float*)d_out;
    float* ws  = (float*)d_ws;
    const int n_pix  = out_size;
    const int planes = n_pix / HW;

    rowmin_kernel<<<dim3(planes), dim3(128), 0, stream>>>(f, ws);
    mindist_kernel<<<dim3((n_pix + 3) / 4), dim3(256), 0, stream>>>(f, ws, out, n_pix);
}

// Round 3
// 16.981 us; speedup vs baseline: 3.0910x; 1.1958x over previous
//
#include <hip/hip_runtime.h>
#include <hip/hip_bf16.h>

// out[i,j] = -min_{x,y}( sqrt((x-i)^2+(y-j)^2) + f[x,y] ),  H=W=96.
// One THREAD per output pixel. Valid pruning bound:
//   sqrt(dx^2+dy^2) + f >= max(|dx|,|dy|) + glob_min  (Chebyshev ring k)
// so once k + glob >= m, ring k and all farther rings cannot improve m.
// Each thread: unconditional 5x5 window (k<=2, compile-time distances),
// then dynamic rings k=3.. while k + glob < m. Single fused kernel: each
// block computes the plane's global min itself (plane is L1/L2-resident).

#define H 96
#define W 96
#define HW (H * W)
#define BLK 256
#define BPP (HW / BLK)   // blocks per plane = 36

__device__ __forceinline__ float wave_min(float m) {
#pragma unroll
    for (int off = 32; off >= 1; off >>= 1)
        m = fminf(m, __shfl_xor(m, off));
    return m;
}

__global__ __launch_bounds__(BLK) void mindist_kernel(
    const float* __restrict__ f, float* __restrict__ out) {
    const int tid  = threadIdx.x;
    const int lane = tid & 63;
    const int wid  = tid >> 6;
    const int plane   = blockIdx.x / BPP;
    const int pixbase = (blockIdx.x % BPP) * BLK;
    const float* fp = f + plane * HW;

    // --- block-wide global min of this plane (coalesced, L2-resident) ---
    float g = 1e30f;
#pragma unroll
    for (int t = 0; t < HW / BLK; ++t)
        g = fminf(g, fp[t * BLK + tid]);
    g = wave_min(g);
    __shared__ float sg[4];
    if (lane == 0) sg[wid] = g;
    __syncthreads();
    const float glob = fminf(fminf(sg[0], sg[1]), fminf(sg[2], sg[3]));

    // --- per-thread pixel ---
    const int p = pixbase + tid;
    const int i = p / W;
    const int j = p - i * W;

    float m = 1e30f;
    // k <= 2: full 5x5 window, distances folded at compile time
#pragma unroll
    for (int dx = -2; dx <= 2; ++dx) {
#pragma unroll
        for (int dy = -2; dy <= 2; ++dy) {
            const int x = i + dx, y = j + dy;
            if ((unsigned)x < H && (unsigned)y < W) {
                const float dist = sqrtf((float)(dx * dx + dy * dy)); // constant
                m = fminf(m, dist + fp[x * W + y]);
            }
        }
    }

    // dynamic Chebyshev rings k = 3..95
    for (int k = 3; k < H && (float)k + glob < m; ++k) {
        const float k2 = (float)(k * k);
        // top/bottom edges of the ring: dy = +-k
        for (int dx = -k; dx <= k; ++dx) {
            const int x = i + dx;
            if ((unsigned)x >= H) continue;
            const float dk = __builtin_amdgcn_sqrtf((float)(dx * dx) + k2);
            const int y0 = j - k, y1 = j + k;
            if ((unsigned)y0 < W) m = fminf(m, dk + fp[x * W + y0]);
            if ((unsigned)y1 < W) m = fminf(m, dk + fp[x * W + y1]);
        }
        // left/right edges: dx = +-k, dy = -k+1..k-1
        for (int dy = -k + 1; dy <= k - 1; ++dy) {
            const int y = j + dy;
            if ((unsigned)y >= W) continue;
            const float dk = __builtin_amdgcn_sqrtf(k2 + (float)(dy * dy));
            const int x0 = i - k, x1 = i + k;
            if ((unsigned)x0 < H) m = fminf(m, dk + fp[x0 * W + y]);
            if ((unsigned)x1 < H) m = fminf(m, dk + fp[x1 * W + y]);
        }
    }

    out[plane * HW + p] = -m;
}

extern "C" void kernel_launch(void* const* d_in, const int* in_sizes, int n_in,
                              void* d_out, int out_size, void* d_ws, size_t ws_size,
                              hipStream_t stream) {
    const float* f = (const float*)d_in[0];
    float* out = (float*)d_out;
    const int n_pix = out_size;              // B*C*H*W
    mindist_kernel<<<dim3(n_pix / BLK), dim3(BLK), 0, stream>>>(f, out);
}

// Round 4
// 16.911 us; speedup vs baseline: 3.1037x; 1.0041x over previous
//
#include <hip/hip_runtime.h>
#include <hip/hip_bf16.h>

// out[i,j] = -min_{x,y}( sqrt((x-i)^2+(y-j)^2) + f[x,y] ),  H=W=96.
// One THREAD per output pixel, one WAVE (64 threads) per block -> 144 blocks
// per plane, no __syncthreads anywhere (glob min via shuffle-only wave_min,
// overlappable with the 5x5 window loads).
// Pruning bound: sqrt(dx^2+dy^2)+f >= max(|dx|,|dy|) + glob_min, so once
// ring index k satisfies k + glob >= m, no farther ring can improve m.

#define H 96
#define W 96
#define HW (H * W)
#define BLK 64
#define BPP (HW / BLK)   // one-wave blocks per plane = 144

__device__ __forceinline__ float wave_min(float m) {
#pragma unroll
    for (int off = 32; off >= 1; off >>= 1)
        m = fminf(m, __shfl_xor(m, off));
    return m;
}

__global__ __launch_bounds__(BLK) void mindist_kernel(
    const float* __restrict__ f, float* __restrict__ out) {
    const int lane    = threadIdx.x;
    const int plane   = blockIdx.x / BPP;
    const int pixbase = (blockIdx.x % BPP) * BLK;
    const float* fp = f + plane * HW;

    // --- per-thread pixel ---
    const int p = pixbase + lane;
    const int i = p / W;
    const int j = p - i * W;

    // 5x5 window (k<=2), distances folded at compile time; these loads can
    // issue concurrently with the glob-reduce loads below (no barrier).
    float m = 1e30f;
#pragma unroll
    for (int dx = -2; dx <= 2; ++dx) {
#pragma unroll
        for (int dy = -2; dy <= 2; ++dy) {
            const int x = i + dx, y = j + dy;
            if ((unsigned)x < H && (unsigned)y < W) {
                const float dist = sqrtf((float)(dx * dx + dy * dy)); // const
                m = fminf(m, dist + fp[x * W + y]);
            }
        }
    }

    // --- wave-wide global min of the plane (float4, coalesced, L2-resident) ---
    const float4* fp4 = (const float4*)fp;
    float g = 1e30f;
#pragma unroll
    for (int t = 0; t < HW / 4 / BLK; ++t) {   // 36 iterations
        const float4 v = fp4[t * BLK + lane];
        g = fminf(g, fminf(fminf(v.x, v.y), fminf(v.z, v.w)));
    }
    const float glob = wave_min(g);

    // --- dynamic Chebyshev rings k = 3.. while k + glob < m ---
    for (int k = 3; k < H && (float)k + glob < m; ++k) {
        const float k2 = (float)(k * k);
        // top/bottom edges: dy = +-k
        const int y0 = j - k, y1 = j + k;
        for (int dx = -k; dx <= k; ++dx) {
            const int x = i + dx;
            if ((unsigned)x >= H) continue;
            const float dk = __builtin_amdgcn_sqrtf((float)(dx * dx) + k2);
            const float* row = fp + x * W;
            if ((unsigned)y0 < W) m = fminf(m, dk + row[y0]);
            if ((unsigned)y1 < W) m = fminf(m, dk + row[y1]);
        }
        // left/right edges: dx = +-k, dy = -k+1..k-1
        const float* r0 = fp + (i - k) * W;
        const float* r1 = fp + (i + k) * W;
        const bool v0 = (unsigned)(i - k) < H, v1 = (unsigned)(i + k) < H;
        for (int dy = -k + 1; dy <= k - 1; ++dy) {
            const int y = j + dy;
            if ((unsigned)y >= W) continue;
            const float dk = __builtin_amdgcn_sqrtf(k2 + (float)(dy * dy));
            if (v0) m = fminf(m, dk + r0[y]);
            if (v1) m = fminf(m, dk + r1[y]);
        }
    }

    out[plane * HW + p] = -m;
}

extern "C" void kernel_launch(void* const* d_in, const int* in_sizes, int n_in,
                              void* d_out, int out_size, void* d_ws, size_t ws_size,
                              hipStream_t stream) {
    const float* f = (const float*)d_in[0];
    float* out = (float*)d_out;
    const int n_pix = out_size;              // B*C*H*W
    mindist_kernel<<<dim3(n_pix / BLK), dim3(BLK), 0, stream>>>(f, out);
}